// Round 9
// baseline (222.645 us; speedup 1.0000x reference)
//
#include <hip/hip_runtime.h>
#include <hip/hip_bf16.h>

#define T_  30
#define B_  64
#define V_  32
#define F_  128
#define L_  64
#define LF_ 64
#define TH_ 20
#define H_  4
#define HD_ 32

typedef __attribute__((ext_vector_type(4))) short bf16x4;   // 4 bf16 = 2 VGPR
typedef __attribute__((ext_vector_type(4))) float f32x4;

// K=16 bf16 MFMA (v_mfma_f32_16x16x16_bf16), CDNA2 "1k" builtin spelling.
// Fragment maps (validated r4-r7 via the C-identity chain):
//   A[m=lane&15][k=(lane>>4)*4+j]   B[k=(lane>>4)*4+j][n=lane&15]
//   C[m=(lane>>4)*4+r][n=lane&15]
// => producer C[x][y] feeds consumer B(k=x,n=y) or A(m=y,k=x), contracting x.
__device__ __forceinline__ f32x4 mfma16(bf16x4 a, bf16x4 b, f32x4 c) {
#if defined(__HIP_DEVICE_COMPILE__)
    return __builtin_amdgcn_mfma_f32_16x16x16bf16_1k(a, b, c, 0, 0, 0);
#else
    (void)a; (void)b; return c;
#endif
}

__device__ __forceinline__ float bf1(unsigned short u) {
    unsigned int x = ((unsigned int)u) << 16; float f; __builtin_memcpy(&f, &x, 4); return f;
}
__device__ __forceinline__ unsigned int cvtpk(float a, float b) {
    __hip_bfloat162 h = __float22bfloat162_rn(make_float2(a, b));
    unsigned int r; __builtin_memcpy(&r, &h, 4); return r;
}
__device__ __forceinline__ bf16x4 pk4(f32x4 v) {
    uint2 u = { cvtpk(v[0], v[1]), cvtpk(v[2], v[3]) };
    bf16x4 r; __builtin_memcpy(&r, &u, 8); return r;
}
__device__ __forceinline__ bf16x4 pk4s(f32x4 v, float s) {
    uint2 u = { cvtpk(v[0] * s, v[1] * s), cvtpk(v[2] * s, v[3] * s) };
    bf16x4 r; __builtin_memcpy(&r, &u, 8); return r;
}
// XOR-granule swizzle on a [32 r][128 c] ushort tile (granule = 8 ushorts).
__device__ __forceinline__ int swz128(int r, int c) { return r * 128 + (c ^ ((r & 7) << 3)); }
// Load a 4-element fragment row-chunk M[row][col..col+3] (elemOff = row*ld+col).
__device__ __forceinline__ bf16x4 ldfrag(const void* M, int elemOff, bool isBf16) {
    if (isBf16) return *(const bf16x4*)((const unsigned short*)M + elemOff);
    const float* p = (const float*)M + elemOff;
    float4 x = *(const float4*)p;
    uint2 u = { cvtpk(x.x, x.y), cvtpk(x.z, x.w) };
    bf16x4 r; __builtin_memcpy(&r, &u, 8); return r;
}

// Wave = one (bv, head). Block = 512 threads = 2 bv x 4 heads; grid 1024.
// Entire per-head chain is register-resident via the K=16 fragment identity:
//   weights/lanes/veh loaded as fragments from global (L2-warm after first
//   blocks); K-proj C[f][l] -> scores-A/B; Q-proj C[g][t] -> scores-B;
//   scores C[l][t] -> PV-B; V-proj C[l][f] -> PV-A; PV C[f][t] -> E-B via a
//   16KB LDS O-exchange (E contracts all 128 f across heads).
// ONE barrier per block. No staging, no sK/sQ, no convoys.
__global__ __launch_bounds__(512, 4)
void lane_attn_kernel(const void* __restrict__ veh,    // [T,B,V,F]
                      const void* __restrict__ lanes,  // [B,V,L,LF]
                      const void* __restrict__ maskp,  // [TH,B,V,L] uint8 or int32 (probed)
                      const void* __restrict__ Wk, const void* __restrict__ Wv,
                      const void* __restrict__ Wq, const void* __restrict__ Wc,
                      float* __restrict__ outp)        // [T,B,V,F] fp32
{
    const int tid   = threadIdx.x;
    const int w     = tid >> 6;
    const int bvloc = w >> 2;          // 0/1: which bv of this block
    const int head  = w & 3;
    const int bv    = blockIdx.x * 2 + bvloc;
    const int lane  = tid & 63;
    const int quad  = lane >> 4;
    const int lm    = lane & 15;
    const int q4    = quad * 4;
    const int fbase = head * 32;

    __shared__ __align__(16) unsigned short sO[2][4096];   // [bvloc][t 32][f 128] swizzled

    // ---------- probes (wave-uniform) ----------
    const unsigned short* vh16 = (const unsigned short*)veh;
    const int field = (vh16[2 * lane] >> 7) & 0xFF;
    const bool isBf16 = __popcll(__ballot(field >= 100 && field <= 130)) >= 32;
    const unsigned char* mbp = (const unsigned char*)maskp;
    const bool maskByte = (__ballot(mbp[4 * lane + 1] != 0) != 0ULL);

    // ---------- mask OR over TH (l = lane) -> wave-uniform bitmask ----------
    bool ok;
    {
        const int* mi = (const int*)maskp;
        int o = 0;
        #pragma unroll
        for (int th = 0; th < TH_; ++th) {
            const size_t e = (size_t)th * (B_ * V_ * L_) + (size_t)bv * L_ + lane;
            o |= maskByte ? (int)mbp[e] : mi[e];
        }
        ok = (o != 0);
    }
    const unsigned long long mok = __ballot(ok);   // bit l = mask for lane-row l

    const void* lanesBV = isBf16
        ? (const void*)((const unsigned short*)lanes + (size_t)bv * (L_ * LF_))
        : (const void*)((const float*)lanes + (size_t)bv * (L_ * LF_));

    // ---------- K & V projection (contract c over LF=64, 4 k-chunks) ----------
    // K swapped:  C[f][l] = mfma16(A=Wk[f][c], B=lanes^T[c][l])
    // V unswapped:C[l][f] = mfma16(A=lanes[l][c], B=Wv^T[c][f])
    bf16x4 KB[2][4], VA[4][2];     // KB[ft][lt]: scores A/B; VA[lt][ft]: PV A
    {
        f32x4 accK[2][4], accV[4][2];
        #pragma unroll
        for (int ft = 0; ft < 2; ++ft)
            #pragma unroll
            for (int lt = 0; lt < 4; ++lt) { accK[ft][lt] = (f32x4)0.f; accV[lt][ft] = (f32x4)0.f; }
        #pragma unroll
        for (int ct = 0; ct < 4; ++ct) {
            bf16x4 wk[2], wv[2], lb[4];
            #pragma unroll
            for (int ft = 0; ft < 2; ++ft) {
                wk[ft] = ldfrag(Wk, (fbase + ft * 16 + lm) * 64 + ct * 16 + q4, isBf16);
                wv[ft] = ldfrag(Wv, (fbase + ft * 16 + lm) * 64 + ct * 16 + q4, isBf16);
            }
            #pragma unroll
            for (int lt = 0; lt < 4; ++lt)
                lb[lt] = ldfrag(lanesBV, (lt * 16 + lm) * 64 + ct * 16 + q4, isBf16);
            #pragma unroll
            for (int ft = 0; ft < 2; ++ft)
                #pragma unroll
                for (int lt = 0; lt < 4; ++lt) {
                    accK[ft][lt] = mfma16(wk[ft], lb[lt], accK[ft][lt]);  // C[f][l]
                    accV[lt][ft] = mfma16(lb[lt], wv[ft], accV[lt][ft]);  // C[l][f]
                }
        }
        #pragma unroll
        for (int ft = 0; ft < 2; ++ft)
            #pragma unroll
            for (int lt = 0; lt < 4; ++lt) { KB[ft][lt] = pk4(accK[ft][lt]); VA[lt][ft] = pk4(accV[lt][ft]); }
    }

    // ---------- Q projection (swapped; contract f over F=128, 8 k-chunks) ----------
    // C[g][t] = mfma16(A=Wq[g][f], B=veh^T[f][t]); pre-scaled by 1/sqrt(32).
    bf16x4 QB[2][2];               // QB[gt][tt]: scores B (k=g == head-f)
    {
        f32x4 accQ[2][2];
        accQ[0][0] = (f32x4)0.f; accQ[0][1] = (f32x4)0.f;
        accQ[1][0] = (f32x4)0.f; accQ[1][1] = (f32x4)0.f;
        #pragma unroll
        for (int kt = 0; kt < 8; ++kt) {
            bf16x4 wq[2], vb[2];
            #pragma unroll
            for (int gt = 0; gt < 2; ++gt)
                wq[gt] = ldfrag(Wq, (fbase + gt * 16 + lm) * 128 + kt * 16 + q4, isBf16);
            #pragma unroll
            for (int tt = 0; tt < 2; ++tt) {
                const int t = tt * 16 + lm;
                bf16x4 z = { 0, 0, 0, 0 };
                vb[tt] = (t < T_)
                    ? ldfrag(veh, (int)(((size_t)t * (B_ * V_) + bv) * F_) + kt * 16 + q4, isBf16)
                    : z;
            }
            #pragma unroll
            for (int gt = 0; gt < 2; ++gt)
                #pragma unroll
                for (int tt = 0; tt < 2; ++tt) accQ[gt][tt] = mfma16(wq[gt], vb[tt], accQ[gt][tt]);
        }
        const float sc = 0.17677669529663687f;   // 1/sqrt(32)
        #pragma unroll
        for (int gt = 0; gt < 2; ++gt)
            #pragma unroll
            for (int tt = 0; tt < 2; ++tt) QB[gt][tt] = pk4s(accQ[gt][tt], sc);
    }

    // ---------- Scores: C[l][t] = mfma16(A=K(C^T), B=Q(C)) over 2 f-chunks ----------
    // ---------- exp/mask + row-sum -> unnormalized P fragments + inv[tt] ----------
    bf16x4 PB[4][2];               // PB[lt][tt]: PV B (k=l)
    float inv[2];
    {
        float psum[2] = { 0.f, 0.f };
        #pragma unroll
        for (int lt = 0; lt < 4; ++lt) {
            const unsigned int m4 = (unsigned int)((mok >> (lt * 16 + q4)) & 0xFULL);
            #pragma unroll
            for (int tt = 0; tt < 2; ++tt) {
                f32x4 s = (f32x4)0.f;
                #pragma unroll
                for (int ft = 0; ft < 2; ++ft) s = mfma16(KB[ft][lt], QB[ft][tt], s);
                const bool tok = (tt * 16 + lm) < T_;
                float e0 = (tok && (m4 & 1u)) ? __expf(s[0]) : 0.f;
                float e1 = (tok && (m4 & 2u)) ? __expf(s[1]) : 0.f;
                float e2 = (tok && (m4 & 4u)) ? __expf(s[2]) : 0.f;
                float e3 = (tok && (m4 & 8u)) ? __expf(s[3]) : 0.f;
                psum[tt] += (e0 + e1) + (e2 + e3);
                uint2 u = { cvtpk(e0, e1), cvtpk(e2, e3) };
                __builtin_memcpy(&PB[lt][tt], &u, 8);
            }
        }
        #pragma unroll
        for (int tt = 0; tt < 2; ++tt) {
            float p = psum[tt];
            p += __shfl_xor(p, 16, 64);
            p += __shfl_xor(p, 32, 64);
            inv[tt] = (p > 0.f) ? 1.f / p : 0.f;   // pad/masked rows -> exact 0
        }
    }

    // ---------- PV: C[f][t] = mfma16(A=V(C^T), B=P(C)) over 4 l-chunks ----------
    // normalize by lane-local inv[tt]; write O to sO[t][f] (swizzled, bf16)
    #pragma unroll
    for (int ft = 0; ft < 2; ++ft)
        #pragma unroll
        for (int tt = 0; tt < 2; ++tt) {
            f32x4 o = (f32x4)0.f;
            #pragma unroll
            for (int lt = 0; lt < 4; ++lt) o = mfma16(VA[lt][ft], PB[lt][tt], o);
            uint2 u = { cvtpk(o[0] * inv[tt], o[1] * inv[tt]),
                        cvtpk(o[2] * inv[tt], o[3] * inv[tt]) };
            *(uint2*)&sO[bvloc][swz128(tt * 16 + lm, fbase + ft * 16 + q4)] = u;
        }

    __syncthreads();   // the ONLY barrier: O complete for both bvs

    // ---------- E: C[g][t] = mfma16(A=Wc[g][f], B=O[f][t]) over 8 f-chunks ----------
    {
        f32x4 acc[2][2];
        acc[0][0] = (f32x4)0.f; acc[0][1] = (f32x4)0.f;
        acc[1][0] = (f32x4)0.f; acc[1][1] = (f32x4)0.f;
        #pragma unroll
        for (int kt = 0; kt < 8; ++kt) {
            bf16x4 wc[2], ob[2];
            #pragma unroll
            for (int gt = 0; gt < 2; ++gt)
                wc[gt] = ldfrag(Wc, (fbase + gt * 16 + lm) * 128 + kt * 16 + q4, isBf16);
            #pragma unroll
            for (int tt = 0; tt < 2; ++tt) {
                uint2 u = *(const uint2*)&sO[bvloc][swz128(tt * 16 + lm, kt * 16 + q4)];
                __builtin_memcpy(&ob[tt], &u, 8);
            }
            #pragma unroll
            for (int gt = 0; gt < 2; ++gt)
                #pragma unroll
                for (int tt = 0; tt < 2; ++tt) acc[gt][tt] = mfma16(wc[gt], ob[tt], acc[gt][tt]);
        }
        // epilogue: +residual (fp32-exact), float4 stores of 4 consecutive g
        #pragma unroll
        for (int gt = 0; gt < 2; ++gt)
            #pragma unroll
            for (int tt = 0; tt < 2; ++tt) {
                const int t = tt * 16 + lm;
                if (t < T_) {
                    const size_t off = ((size_t)t * (B_ * V_) + bv) * F_ + fbase + gt * 16 + q4;
                    float4 r;
                    if (isBf16) {
                        ushort4 u = *(const ushort4*)((const unsigned short*)veh + off);
                        r = make_float4(bf1(u.x), bf1(u.y), bf1(u.z), bf1(u.w));
                    } else {
                        r = *(const float4*)((const float*)veh + off);
                    }
                    float4 o = make_float4(acc[gt][tt][0] + r.x, acc[gt][tt][1] + r.y,
                                           acc[gt][tt][2] + r.z, acc[gt][tt][3] + r.w);
                    *(float4*)&outp[off] = o;
                }
            }
    }
}

extern "C" void kernel_launch(void* const* d_in, const int* in_sizes, int n_in,
                              void* d_out, int out_size, void* d_ws, size_t ws_size,
                              hipStream_t stream) {
    (void)in_sizes; (void)n_in; (void)out_size; (void)d_ws; (void)ws_size;
    lane_attn_kernel<<<dim3(B_ * V_ / 2), dim3(512), 0, stream>>>(
        d_in[0], d_in[1], d_in[2], d_in[3], d_in[4], d_in[5], d_in[6],
        (float*)d_out);
}